// Round 1
// baseline (10857.573 us; speedup 1.0000x reference)
//
#include <hip/hip_runtime.h>
#include <cstdint>
#include <cstddef>

// LSTM: B=128, T=512, I=1024, H=1024. fp32 in/out, bf16 MFMA internally.
// Plan:
//  1. pack_w: W_{i*,h*} fp32 [K][H] -> bf16 Bt layout [jc][k], jc = jh*4+gate
//     (gate-interleaved so a 32-wide column tile = 8 h-columns x 4 gates).
//  2. pack_bias: b_in[jc] = b_x[g][jh] + b_h[g][jh].
//  3. per chunk of Tc timesteps:
//     convert_x  : x fp32 -> xb bf16 rows r=b*Tc+tc
//     gemm_xproj : xp[tc][b][jc] = xb @ Winp + bias   (MFMA 16x16x32 bf16)
//     lstm_step  : gates = xp[tc] + h @ Whp; fused cell update -> c,h (fp32),
//                  h also re-split to bf16 for the next step's A operand.
//  4. finalize: d_out = [h | c].
// GEMMs are LDS-free: per-lane 16B fragment loads, 4 lanes share a 64B row
// segment -> coalesced; B-fragments come from the K-major packed layout.

#define B_  128
#define T_  512
#define I_  1024
#define H_  1024
#define G4_ 4096

typedef __attribute__((ext_vector_type(8))) short short8;   // 8 bf16 (4 VGPR)
typedef __attribute__((ext_vector_type(4))) float f32x4;

static __device__ __forceinline__ unsigned short f2bf(float f) {
    unsigned u = __builtin_bit_cast(unsigned, f);
    u += 0x7fffu + ((u >> 16) & 1u);          // RNE (inputs finite)
    return (unsigned short)(u >> 16);
}
static __device__ __forceinline__ float sigm(float x) {
    return 1.0f / (1.0f + exp2f(-1.4426950408889634f * x));
}
static __device__ __forceinline__ float tanh_(float x) {
    float e = exp2f(2.8853900817779268f * x);  // exp(2x)
    return 1.0f - 2.0f / (e + 1.0f);
}
static __device__ __forceinline__ f32x4 mfma16(short8 a, short8 b, f32x4 c) {
    return __builtin_amdgcn_mfma_f32_16x16x32_bf16(a, b, c, 0, 0, 0);
}

// ---- pack one 1024x1024 fp32 weight into bf16 Bt[jc][k] for its gate g ----
__global__ __launch_bounds__(256) void pack_w(const float* __restrict__ W,
                                              unsigned short* __restrict__ outBt,
                                              int g) {
    __shared__ float tile[64][65];
    const int tid = threadIdx.x;
    const int k0 = blockIdx.y * 64;
    const int j0 = blockIdx.x * 64;
    {   // coalesced load 64x64
        const int r  = tid >> 2;
        const int c0 = (tid & 3) * 16;
        const float* src = W + (size_t)(k0 + r) * H_ + j0 + c0;
        #pragma unroll
        for (int q = 0; q < 4; ++q) {
            float4 v = *(const float4*)(src + q * 4);
            tile[r][c0 + q*4 + 0] = v.x;
            tile[r][c0 + q*4 + 1] = v.y;
            tile[r][c0 + q*4 + 2] = v.z;
            tile[r][c0 + q*4 + 3] = v.w;
        }
    }
    __syncthreads();
    {   // transposed write: out[(jh*4+g)*1024 + k]
        const int jl   = tid >> 2;
        const int kseg = (tid & 3) * 16;
        unsigned short* orow = outBt + ((size_t)(j0 + jl) * 4 + g) * 1024 + (k0 + kseg);
        #pragma unroll
        for (int q = 0; q < 16; q += 4) {
            ushort4 u;
            u.x = f2bf(tile[kseg + q + 0][jl]);
            u.y = f2bf(tile[kseg + q + 1][jl]);
            u.z = f2bf(tile[kseg + q + 2][jl]);
            u.w = f2bf(tile[kseg + q + 3][jl]);
            *(ushort4*)(orow + q) = u;
        }
    }
}

__global__ __launch_bounds__(256) void pack_bias(
    const float* b0x, const float* b0h, const float* b1x, const float* b1h,
    const float* b2x, const float* b2h, const float* b3x, const float* b3h,
    float* __restrict__ out) {
    int jc = blockIdx.x * 256 + threadIdx.x;   // [0,4096)
    int g = jc & 3, jh = jc >> 2;
    const float* bx = (g == 0) ? b0x : (g == 1) ? b1x : (g == 2) ? b2x : b3x;
    const float* bh = (g == 0) ? b0h : (g == 1) ? b1h : (g == 2) ? b2h : b3h;
    out[jc] = bx[jh] + bh[jh];
}

// ---- x fp32 -> xb bf16, chunk-local rows r = b*Tcc + tc ----
__global__ __launch_bounds__(256) void convert_x(const float* __restrict__ x,
                                                 unsigned short* __restrict__ xb,
                                                 int t0, int Tcc) {
    int e = blockIdx.x * 256 + threadIdx.x;    // one thread = 8 elements
    int i = (e & 127) << 3;
    int r = e >> 7;
    int b = r / Tcc, tc = r - b * Tcc;
    const float* s = x + (size_t)(b * T_ + t0 + tc) * I_ + i;
    float4 v0 = *(const float4*)s;
    float4 v1 = *(const float4*)(s + 4);
    ushort4 u0; u0.x = f2bf(v0.x); u0.y = f2bf(v0.y); u0.z = f2bf(v0.z); u0.w = f2bf(v0.w);
    ushort4 u1; u1.x = f2bf(v1.x); u1.y = f2bf(v1.y); u1.z = f2bf(v1.z); u1.w = f2bf(v1.w);
    unsigned short* d = xb + (size_t)r * I_ + i;
    *(ushort4*)d = u0;
    *(ushort4*)(d + 4) = u1;
}

// ---- phase 1: xp[tc][b][jc] = xb @ Winp + bias ----
// grid (32, 2*Tcc); block 256 = 4 waves; wave w: 64 rows x 32 cols.
__global__ __launch_bounds__(256) void gemm_xproj(
    const unsigned short* __restrict__ A,    // [128*Tcc][1024] bf16
    const unsigned short* __restrict__ Bt,   // [4096][1024] bf16 (Winp)
    const float* __restrict__ bias,          // [4096]
    float* __restrict__ xp,                  // [Tcc*128*4096] fp32
    int Tcc) {
    const int tid = threadIdx.x;
    const int w = tid >> 6, l = tid & 63;
    const int l15 = l & 15, hi = l >> 4;
    const int row0 = blockIdx.y * 64;
    const int col0 = blockIdx.x * 128 + w * 32;
    const int k0 = hi * 8;
    f32x4 acc[4][2] = {};
    const unsigned short* a0 = A  + (size_t)(row0 + l15) * 1024 + k0;
    const unsigned short* b0 = Bt + (size_t)(col0 + l15) * 1024 + k0;
    for (int ks = 0; ks < 1024; ks += 32) {
        short8 a[4], bb[2];
        #pragma unroll
        for (int mi = 0; mi < 4; ++mi) a[mi]  = *(const short8*)(a0 + (size_t)mi * 16 * 1024 + ks);
        #pragma unroll
        for (int ni = 0; ni < 2; ++ni) bb[ni] = *(const short8*)(b0 + (size_t)ni * 16 * 1024 + ks);
        #pragma unroll
        for (int mi = 0; mi < 4; ++mi)
            #pragma unroll
            for (int ni = 0; ni < 2; ++ni)
                acc[mi][ni] = mfma16(a[mi], bb[ni], acc[mi][ni]);
    }
    #pragma unroll
    for (int mi = 0; mi < 4; ++mi) {
        #pragma unroll
        for (int ni = 0; ni < 2; ++ni) {
            int colg = col0 + ni * 16 + l15;
            float bs = bias[colg];
            #pragma unroll
            for (int j = 0; j < 4; ++j) {
                int r = row0 + mi * 16 + hi * 4 + j;     // r = b*Tcc + tc
                int b = r / Tcc, tc = r - b * Tcc;
                xp[(size_t)(tc * 128 + b) * G4_ + colg] = acc[mi][ni][j] + bs;
            }
        }
    }
}

// ---- phase 2: one timestep. grid (128, 2); block 256 = 4 waves (split rows).
__global__ __launch_bounds__(256) void lstm_step(
    const unsigned short* __restrict__ hb_in,  // [128][1024] bf16
    const unsigned short* __restrict__ Whp,    // [4096][1024] bf16
    const float* __restrict__ xp,              // chunk [Tcc][128][4096]
    int tc,
    float* __restrict__ c,                     // [128][1024] fp32 (in/out)
    float* __restrict__ hf,                    // [128][1024] fp32 (out)
    unsigned short* __restrict__ hb_out) {     // [128][1024] bf16 (out)
    const int tid = threadIdx.x;
    const int w = tid >> 6, l = tid & 63;
    const int l15 = l & 15, hi = l >> 4;
    const int row0 = blockIdx.y * 64;          // batch tile
    const int col0 = blockIdx.x * 32;          // packed gate-col tile
    const int k0 = hi * 8;
    f32x4 acc[2] = {};
    const unsigned short* ap = hb_in + (size_t)(row0 + w * 16 + l15) * 1024 + k0;
    const unsigned short* bp = Whp   + (size_t)(col0 + l15) * 1024 + k0;
    #pragma unroll 4
    for (int ks = 0; ks < 1024; ks += 32) {
        short8 a  = *(const short8*)(ap + ks);
        short8 b0 = *(const short8*)(bp + ks);
        short8 b1 = *(const short8*)(bp + 16 * 1024 + ks);
        acc[0] = mfma16(a, b0, acc[0]);
        acc[1] = mfma16(a, b1, acc[1]);
    }
    // gates -> LDS (need all 4 gates of a (b,jh) in one thread)
    __shared__ float gl[64][33];
    const float* xpb = xp + ((size_t)tc * 128 + row0) * G4_ + col0;
    #pragma unroll
    for (int ni = 0; ni < 2; ++ni) {
        #pragma unroll
        for (int j = 0; j < 4; ++j) {
            int row_l = w * 16 + hi * 4 + j;
            int cl = ni * 16 + l15;
            gl[row_l][cl] = acc[ni][j] + xpb[(size_t)row_l * G4_ + cl];
        }
    }
    __syncthreads();
    #pragma unroll
    for (int s = 0; s < 2; ++s) {
        int q = tid + s * 256;                 // 64 rows x 8 jh = 512 items
        int row_l = q >> 3, jhl = q & 7;
        float gi = gl[row_l][jhl * 4 + 0];
        float gf = gl[row_l][jhl * 4 + 1];
        float gg = gl[row_l][jhl * 4 + 2];
        float go = gl[row_l][jhl * 4 + 3];
        int b  = row0 + row_l;
        int jh = blockIdx.x * 8 + jhl;
        size_t idx = (size_t)b * H_ + jh;
        float co = c[idx];
        float it = sigm(gi), ft = sigm(gf), gt = tanh_(gg), ot = sigm(go);
        float cn = ft * co + it * gt;
        float hn = ot * tanh_(cn);
        c[idx] = cn;
        hf[idx] = hn;
        hb_out[idx] = f2bf(hn);
    }
}

__global__ __launch_bounds__(256) void finalize(const float* __restrict__ hf,
                                                const float* __restrict__ c,
                                                float* __restrict__ out) {
    int i = blockIdx.x * 256 + threadIdx.x;    // 32768 float4s per half
    ((float4*)out)[i]         = ((const float4*)hf)[i];
    ((float4*)out)[32768 + i] = ((const float4*)c)[i];
}

extern "C" void kernel_launch(void* const* d_in, const int* in_sizes, int n_in,
                              void* d_out, int out_size, void* d_ws, size_t ws_size,
                              hipStream_t stream) {
    const float* x = (const float*)d_in[0];
    // setup_inputs order: x, W_ii, W_hi, W_if, W_hf, W_ig, W_hg, W_io, W_ho,
    //                     b_ii, b_hi, b_if, b_hf, b_ig, b_hg, b_io, b_ho
    const float* Wx[4] = {(const float*)d_in[1], (const float*)d_in[3],
                          (const float*)d_in[5], (const float*)d_in[7]};
    const float* Wh[4] = {(const float*)d_in[2], (const float*)d_in[4],
                          (const float*)d_in[6], (const float*)d_in[8]};
    const float* bx[4] = {(const float*)d_in[9],  (const float*)d_in[11],
                          (const float*)d_in[13], (const float*)d_in[15]};
    const float* bh[4] = {(const float*)d_in[10], (const float*)d_in[12],
                          (const float*)d_in[14], (const float*)d_in[16]};

    char* p = (char*)d_ws;
    auto take = [&](size_t bytes) {
        char* q = p; p += (bytes + 255) & ~(size_t)255; return q;
    };
    unsigned short* Winp = (unsigned short*)take((size_t)G4_ * 1024 * 2);
    unsigned short* Whp  = (unsigned short*)take((size_t)G4_ * 1024 * 2);
    float*          bias = (float*)take(G4_ * 4);
    unsigned short* hb0  = (unsigned short*)take((size_t)B_ * H_ * 2);
    unsigned short* hb1  = (unsigned short*)take((size_t)B_ * H_ * 2);
    float*          cbuf = (float*)take((size_t)B_ * H_ * 4);
    float*          hfb  = (float*)take((size_t)B_ * H_ * 4);
    size_t fixed = (size_t)(p - (char*)d_ws);
    // per-timestep chunk cost: xb (bf16) + xp (fp32) rows
    size_t per = (size_t)B_ * I_ * 2 + (size_t)B_ * G4_ * 4 + 512;
    size_t avail = ws_size > fixed ? ws_size - fixed : 0;
    int Tc = (int)(avail / per);
    if (Tc > T_) Tc = T_;
    if (Tc < 1) Tc = 1;                         // needs ~20.5 MB of ws minimum
    unsigned short* xb  = (unsigned short*)take((size_t)Tc * B_ * I_ * 2);
    float*          xpc = (float*)take((size_t)Tc * B_ * G4_ * 4);

    for (int g = 0; g < 4; ++g) {
        pack_w<<<dim3(16, 16), 256, 0, stream>>>(Wx[g], Winp, g);
        pack_w<<<dim3(16, 16), 256, 0, stream>>>(Wh[g], Whp, g);
    }
    pack_bias<<<16, 256, 0, stream>>>(bx[0], bh[0], bx[1], bh[1],
                                      bx[2], bh[2], bx[3], bh[3], bias);
    hipMemsetAsync(hb0, 0, (size_t)B_ * H_ * 2, stream);
    hipMemsetAsync(cbuf, 0, (size_t)B_ * H_ * 4, stream);

    unsigned short* hbufs[2] = {hb0, hb1};
    for (int t0 = 0; t0 < T_; t0 += Tc) {
        int Tcc = (T_ - t0 < Tc) ? (T_ - t0) : Tc;
        convert_x<<<Tcc * 64, 256, 0, stream>>>(x, xb, t0, Tcc);
        gemm_xproj<<<dim3(32, 2 * Tcc), 256, 0, stream>>>(xb, Winp, bias, xpc, Tcc);
        for (int tc = 0; tc < Tcc; ++tc) {
            int t = t0 + tc;
            lstm_step<<<dim3(128, 2), 256, 0, stream>>>(
                hbufs[t & 1], Whp, xpc, tc, cbuf, hfb, hbufs[(t + 1) & 1]);
        }
    }
    finalize<<<128, 256, 0, stream>>>(hfb, cbuf, (float*)d_out);
}